// Round 12
// baseline (819.199 us; speedup 1.0000x reference)
//
#include <hip/hip_runtime.h>
#include <hip/hip_bf16.h>

typedef __hip_bfloat16 bf16;
typedef __attribute__((ext_vector_type(8))) short s8;   // 8 x bf16 MFMA A/B frag
typedef __attribute__((ext_vector_type(4))) short s4;   // 4 x bf16 (8B)
typedef __attribute__((ext_vector_type(4))) float f4;   // MFMA C/D frag

#define N_FEA   3145728   // 2*96*128*128
#define N_EN    196608    // 2*96*32*32
#define N_E1    786432    // 2*96*64*64
#define OUT_EN  3145728
#define OUT_Q   3342336

__device__ __forceinline__ float b2f(bf16 v) { return __bfloat162float(v); }
__device__ __forceinline__ float bs2f(short v) {
    union { unsigned u; float f; } x; x.u = ((unsigned)(unsigned short)v) << 16; return x.f;
}

// -------- pack oc1/oc3 weights for scalar-load conv: [ks][ocg][c][kx][o][ky] --------
__global__ void wpack_sw(const float* __restrict__ w1, const float* __restrict__ w3,
                         float* __restrict__ o1, float* __restrict__ o3) {
    long i = (long)blockIdx.x * 256 + threadIdx.x;
    const long n1 = 2L * 12 * 96 * 72;   // 165888
    if (i < n1) {
        int ky = (int)(i % 3); long t = i / 3;
        int o = (int)(t % 8); t /= 8;
        int kx = (int)(t % 3); t /= 3;
        int c = (int)(t % 96); t /= 96;
        int ocg = (int)(t % 12); int ks = (int)(t / 12);
        o1[i] = w1[((long)(ocg * 8 + o) * 192 + ks * 96 + c) * 9 + ky * 3 + kx];
        return;
    }
    i -= n1;
    const long n3 = 2L * 12 * 48 * 72;   // 82944
    if (i < n3) {
        int ky = (int)(i % 3); long t = i / 3;
        int o = (int)(t % 8); t /= 8;
        int kx = (int)(t % 3); t /= 3;
        int c = (int)(t % 48); t /= 48;
        int ocg = (int)(t % 12); int ks = (int)(t / 12);
        o3[i] = w3[((long)(ocg * 8 + o) * 96 + ks * 48 + c) * 9 + ky * 3 + kx];
    }
}

// -------- pack enc1/enc2 weights for stride-2 scalar conv: [ocg][c][o][ky*3+kx] ----
__global__ void wpack_enc(const float* __restrict__ w1, const float* __restrict__ w2,
                          float* __restrict__ o1, float* __restrict__ o2) {
    long i = (long)blockIdx.x * 256 + threadIdx.x;
    const long n1 = 24L * 96 * 4 * 9;    // 82944 (OCB=4)
    if (i < n1) {
        int k = (int)(i % 9);
        int o = (int)((i / 9) % 4);
        int c = (int)((i / 36) % 96);
        int ocg = (int)(i / (36 * 96));
        o1[i] = w1[((long)(ocg * 4 + o) * 96 + c) * 9 + k];
        return;
    }
    i -= n1;
    const long n2 = 48L * 96 * 2 * 9;    // 82944 (OCB=2)
    if (i < n2) {
        int k = (int)(i % 9);
        int o = (int)((i / 9) % 2);
        int c = (int)((i / 18) % 96);
        int ocg = (int)(i / (18 * 96));
        o2[i] = w2[((long)(ocg * 2 + o) * 96 + c) * 9 + k];
    }
}

// -------- pack dec1/dec2 (ConvT, w=[Cin][Cout][3][3]) -> [ocg][c][o][ky*3+kx] -----
__global__ void wpack_dec(const float* __restrict__ w1, const float* __restrict__ w2,
                          float* __restrict__ o1, float* __restrict__ o2) {
    long i = (long)blockIdx.x * 256 + threadIdx.x;
    const long n1 = 48L * 96 * 2 * 9;    // 82944 (dec1, OCB=2)
    if (i < n1) {
        int k = (int)(i % 9);
        int o = (int)((i / 9) % 2);
        int c = (int)((i / 18) % 96);
        int ocg = (int)(i / (18 * 96));
        o1[i] = w1[((long)c * 96 + ocg * 2 + o) * 9 + k];
        return;
    }
    i -= n1;
    const long n2 = 24L * 96 * 4 * 9;    // 82944 (dec2, OCB=4)
    if (i < n2) {
        int k = (int)(i % 9);
        int o = (int)((i / 9) % 4);
        int c = (int)((i / 36) % 96);
        int ocg = (int)(i / (36 * 96));
        o2[i] = w2[((long)c * 96 + ocg * 4 + o) * 9 + k];
    }
}

// ---- FUSED split-K stride-1 conv + bias + lrelu, 128x128, SGPR weights ----
// Two accumulator sets (half A = in0, half B = in1); final = (bias+accA)+accB
// which matches the old fuse_add_k's (bias + p0) + p1 left-assoc order exactly.
// Thread = 1 col x 2 rows; block = 64-col panel x 8-row strip; grid 768 (3/CU).
// Per-output accumulation order (c asc; kx, o, ky) identical to prior rounds.
template <int OCB>
__global__ __launch_bounds__(256) void conv3x3_fu(
    const float* __restrict__ in0, int c0, int bstr0,
    const float* __restrict__ in1, int c1, int bstr1,
    const float* __restrict__ wsc, const float* __restrict__ bias,
    float* __restrict__ outp, int Cout) {
    const int H = 128, W = 128;
    const int NOC = Cout / OCB;          // 12
    int bid = blockIdx.x;
    const int pan = bid & 1; bid >>= 1;
    const int strip = bid & 15; bid >>= 4;
    const int ocg = bid % NOC;
    const int b = bid / NOC;

    const int ox = pan * 64 + (threadIdx.x & 63);
    const int rg = threadIdx.x >> 6;          // wave index 0..3 (wave-uniform)
    const int oy0 = strip * 8 + rg * 2;
    const int iyb = oy0 - 1;

    bool vy[4];
#pragma unroll
    for (int j = 0; j < 4; ++j) vy[j] = (unsigned)(iyb + j) < (unsigned)H;

    float accA[OCB][2], accB[OCB][2];
#pragma unroll
    for (int o = 0; o < OCB; ++o)
#pragma unroll
        for (int j = 0; j < 2; ++j) { accA[o][j] = 0.f; accB[o][j] = 0.f; }

    // half A
    {
        const float* wq0 = wsc + (long)ocg * c0 * 72;
        const float* pc = in0 + (long)b * bstr0 * H * W + (long)iyb * W;
        for (int c = 0; c < c0; ++c) {
            const float* wq = wq0 + c * 72;
#pragma unroll
            for (int kx = 0; kx < 3; ++kx) {
                const int ix = ox + kx - 1;
                const bool vx = (unsigned)ix < (unsigned)W;
                float rv[4];
#pragma unroll
                for (int j = 0; j < 4; ++j)
                    rv[j] = (vx && vy[j]) ? pc[j * W + ix] : 0.f;
#pragma unroll
                for (int o = 0; o < OCB; ++o) {
#pragma unroll
                    for (int ky = 0; ky < 3; ++ky) {
                        float wz = wq[kx * 24 + o * 3 + ky];   // uniform -> s_load
#pragma unroll
                        for (int j = 0; j < 2; ++j)
                            accA[o][j] = fmaf(rv[j + ky], wz, accA[o][j]);
                    }
                }
            }
            pc += (long)H * W;
        }
    }
    // half B
    {
        const float* wq0 = wsc + ((long)NOC + ocg) * c1 * 72;
        const float* pc = in1 + (long)b * bstr1 * H * W + (long)iyb * W;
        for (int c = 0; c < c1; ++c) {
            const float* wq = wq0 + c * 72;
#pragma unroll
            for (int kx = 0; kx < 3; ++kx) {
                const int ix = ox + kx - 1;
                const bool vx = (unsigned)ix < (unsigned)W;
                float rv[4];
#pragma unroll
                for (int j = 0; j < 4; ++j)
                    rv[j] = (vx && vy[j]) ? pc[j * W + ix] : 0.f;
#pragma unroll
                for (int o = 0; o < OCB; ++o) {
#pragma unroll
                    for (int ky = 0; ky < 3; ++ky) {
                        float wz = wq[kx * 24 + o * 3 + ky];
#pragma unroll
                        for (int j = 0; j < 2; ++j)
                            accB[o][j] = fmaf(rv[j + ky], wz, accB[o][j]);
                    }
                }
            }
            pc += (long)H * W;
        }
    }
#pragma unroll
    for (int o = 0; o < OCB; ++o) {
        float bz = bias[ocg * OCB + o];
        long base = (((long)b * Cout + ocg * OCB + o) * H + oy0) * W + ox;
#pragma unroll
        for (int j = 0; j < 2; ++j) {
            float a = (bz + accA[o][j]) + accB[o][j];
            a = a > 0.f ? a : 0.1f * a;
            outp[base + (long)j * W] = a;
        }
    }
}

// ---- stride-2 direct conv, SGPR weights, no LDS, 1 output px/thread ----
template <int OCB>
__global__ __launch_bounds__(256) void conv_s2_px(
    const float* __restrict__ in, int Cin, int Hin, int Win,
    const float* __restrict__ wsc, const float* __restrict__ bias,
    float* __restrict__ out, int Cout, int relu,
    float* __restrict__ qq, float* __restrict__ qf2) {
    const int Hout = Hin >> 1, Wout = Win >> 1;
    const int rpb = 256 / Wout;              // rows per block (1 px/thread)
    const int strips = Hout / rpb;
    int bid = blockIdx.x;
    const int strip = bid % strips; bid /= strips;
    const int NOC = Cout / OCB;
    const int ocg = bid % NOC;
    const int b = bid / NOC;
    const int tid = threadIdx.x;
    const int ox = tid % Wout;
    const int oy = strip * rpb + tid / Wout;
    const int iy0 = oy * 2 - 1, ix0 = ox * 2 - 1;
    const float* wq0 = wsc + (long)(ocg * Cin) * (OCB * 9);

    float acc[OCB];
#pragma unroll
    for (int o = 0; o < OCB; ++o) acc[o] = bias[ocg * OCB + o];
    const bool vx0 = ix0 >= 0;               // only left col / top row can be OOB
    const bool vy0 = iy0 >= 0;

    const float* pc = in + (long)b * Cin * Hin * Win + (long)iy0 * Win + ix0;
    for (int c = 0; c < Cin; ++c) {
        float rv[3][3];
#pragma unroll
        for (int jr = 0; jr < 3; ++jr) {
            const float* row = pc + jr * Win;
            const bool vr = jr ? true : vy0;
            rv[jr][0] = (vr && vx0) ? row[0] : 0.f;
            rv[jr][1] = vr ? row[1] : 0.f;
            rv[jr][2] = vr ? row[2] : 0.f;
        }
        const float* wq = wq0 + c * (OCB * 9);
#pragma unroll
        for (int o = 0; o < OCB; ++o)
#pragma unroll
            for (int ky = 0; ky < 3; ++ky)
#pragma unroll
                for (int kx = 0; kx < 3; ++kx)
                    acc[o] = fmaf(rv[ky][kx], wq[o * 9 + ky * 3 + kx], acc[o]);
        pc += (long)Hin * Win;
    }
#pragma unroll
    for (int o = 0; o < OCB; ++o) {
        long idx = (((long)b * Cout + ocg * OCB + o) * Hout + oy) * Wout + ox;
        float a = acc[o];
        if (relu) a = a > 0.f ? a : 0.1f * a;
        out[idx] = a;
        if (qq) {
            float qv = rintf(a);
            qq[idx] = qv;
            qf2[idx] = qv;
        }
    }
}

// ---- ConvTranspose2d(96->96,k3,s2,p1,op1): 2x2 output quad per thread, ----
// SGPR weights [ocg][c][o][ky*3+kx], 4 coalesced loads/c serve all 9 taps.
template <int OCB, int HWC>
__global__ __launch_bounds__(256) void convt_quad(
    const float* __restrict__ in, const float* __restrict__ wsc,
    const float* __restrict__ bias, void* __restrict__ out,
    int Hin, int Win, int relu) {
    const int C = 96;
    const int Hout = 2 * Hin, Wout = 2 * Win;
    const int strips = (Hin * Win) / 256;
    int bid = blockIdx.x;
    const int strip = bid % strips; bid /= strips;
    const int NOC = C / OCB;
    const int ocg = bid % NOC;
    const int b = bid / NOC;
    const int idx = strip * 256 + threadIdx.x;
    const int iy = idx / Win, ix = idx % Win;
    const bool vr = (ix + 1) < Win, vd = (iy + 1) < Hin;
    const float* wq0 = wsc + (long)(ocg * C) * (OCB * 9);

    float acc[OCB][4];
#pragma unroll
    for (int o = 0; o < OCB; ++o) {
        float bz = bias[ocg * OCB + o];
#pragma unroll
        for (int j = 0; j < 4; ++j) acc[o][j] = bz;
    }
    const float* pc = in + (long)b * C * Hin * Win + (long)iy * Win + ix;
    for (int c = 0; c < C; ++c) {
        float i00 = pc[0];
        float i01 = vr ? pc[1] : 0.f;
        float i10 = vd ? pc[Win] : 0.f;
        float i11 = (vr && vd) ? pc[Win + 1] : 0.f;
        const float* wq = wq0 + c * (OCB * 9);
#pragma unroll
        for (int o = 0; o < OCB; ++o) {
            const float* w = wq + o * 9;
            acc[o][0] = fmaf(i00, w[4], acc[o][0]);
            acc[o][1] = fmaf(i01, w[3], fmaf(i00, w[5], acc[o][1]));
            acc[o][2] = fmaf(i10, w[1], fmaf(i00, w[7], acc[o][2]));
            acc[o][3] = fmaf(i11, w[0],
                        fmaf(i10, w[2],
                        fmaf(i01, w[6],
                        fmaf(i00, w[8], acc[o][3]))));
        }
        pc += (long)Hin * Win;
    }
#pragma unroll
    for (int o = 0; o < OCB; ++o) {
        int oc = ocg * OCB + o;
#pragma unroll
        for (int j = 0; j < 4; ++j) {
            float a = acc[o][j];
            if (relu) a = a > 0.f ? a : 0.1f * a;
            int oy = 2 * iy + (j >> 1), ox2 = 2 * ix + (j & 1);
            if (HWC)
                ((bf16*)out)[((long)b * Hout * Wout + (long)oy * Wout + ox2) * 96 + oc] =
                    __float2bfloat16(a);
            else
                ((float*)out)[(((long)b * C + oc) * Hout + oy) * Wout + ox2] = a;
        }
    }
}

// -------- combined weight transforms: 3x MFMA-B pack + dcn MFMA-B pack ------
__device__ __forceinline__ void packw(const float* __restrict__ w, bf16* __restrict__ wP,
                                      int Cin, int swap, long i) {
    const int cpt = Cin >> 5;
    int e = (int)(i & 7);
    int n16 = (int)((i >> 3) & 15);
    int q = (int)((i >> 7) & 3);
    long t = i >> 9;
    int ci = (int)(t % cpt); t /= cpt;
    int tap = (int)(t % 9);
    int g = (int)(t / 9);
    int oc = g * 16 + n16;
    int c = ci * 32 + q * 8 + e;
    int cs = swap ? (c + Cin / 2) % Cin : c;
    wP[i] = __float2bfloat16(w[((long)oc * Cin + cs) * 9 + tap]);
}
__global__ void wxform_all(const float* __restrict__ coffw, const float* __restrict__ ref1w,
                           const float* __restrict__ ref2w, const float* __restrict__ dcnw,
                           bf16* __restrict__ p_coff, bf16* __restrict__ p_ref1,
                           bf16* __restrict__ p_ref2, bf16* __restrict__ p_dcn) {
    const long n1 = 124416, n2 = 165888, n3 = 82944, n4 = 82944;
    long i = (long)blockIdx.x * 256 + threadIdx.x;
    if (i < n1) { packw(coffw, p_coff, 96, 0, i); return; }
    i -= n1;
    if (i < n2) { packw(ref1w, p_ref1, 192, 1, i); return; }
    i -= n2;
    if (i < n3) { packw(ref2w, p_ref2, 96, 0, i); return; }
    i -= n3;
    if (i < n4) {
        // dcn: K=864 GEMM-B pack [g][ci][lane][8]; k' = ci*32+q*8+e with
        // K-ordering k' = kk*96 + c  (matches deform's [px][kk][c] LDS layout)
        int e = (int)(i & 7);
        int n16 = (int)((i >> 3) & 15);
        int q = (int)((i >> 7) & 3);
        long t = i >> 9;
        int ci = (int)(t % 27);
        int g = (int)(t / 27);
        int kp = ci * 32 + q * 8 + e;     // k' in [0,864)
        int c = kp % 96, kk = kp / 96;
        p_dcn[i] = __float2bfloat16(dcnw[(long)(g * 16 + n16) * 864 + c * 9 + kk]);
    }
}

// -------- pack fp32 NCHW (96 ch) -> bf16 HWC [b][y][x][Cs] at channel offset --------
__global__ void pack_hwc(const float* __restrict__ src, bf16* __restrict__ dst,
                         int HW, int Cs, int coff) {
    long i = (long)blockIdx.x * 256 + threadIdx.x;
    if (i >= 2L * 96 * HW) return;
    int px = (int)(i % HW);
    long t = i / HW;
    int c = (int)(t % 96);
    int b = (int)(t / 96);
    dst[((long)b * HW + px) * Cs + coff + c] = __float2bfloat16(src[i]);
}

// ----------------- MFMA implicit-GEMM 3x3 conv (stride 1, 128x128) -----------------
// 512-thread blocks, 8 waves: wave = (og-half, 16-px m-tile). Same MFMA sequence
// per output as the 4-wave version (bit-identical); 2x waves/SIMD for latency.
template <int EPI>
__global__ __launch_bounds__(512) void mconv(
    const bf16* __restrict__ X, const bf16* __restrict__ wP,
    const float* __restrict__ bias, void* __restrict__ out,
    const bf16* __restrict__ res,
    int Cin, int Cout, int H, int W, int relu) {
    const int HW = H * W;
    const int NG = Cout >> 4, split = (NG + 1) >> 1;
    int bid = blockIdx.x;
    const int nb = HW >> 6;
    const int pxb = (bid % nb) << 6;
    const int b = bid / nb;
    const int wave = threadIdx.x >> 6, lane = threadIdx.x & 63;
    const int mq = wave & 3;                  // 16-px m-tile 0..3
    const int og0 = (wave >> 2) ? split : 0;
    const int og1 = (wave >> 2) ? NG : split;
    const int q = lane >> 4, n16 = lane & 15;
    const int pA = pxb + mq * 16 + n16;
    const int oyA = pA / W, oxA = pA % W;
    const long ib = (long)b * HW * Cin;
    f4 acc[5];
    const f4 z4 = {0.f, 0.f, 0.f, 0.f};
#pragma unroll
    for (int g = 0; g < 5; ++g) acc[g] = z4;
    const s8 z8 = {0, 0, 0, 0, 0, 0, 0, 0};
    const int cpt = Cin >> 5;
    const int lofs = lane << 3;
    for (int tap = 0; tap < 9; ++tap) {
        const int ky = tap / 3 - 1, kx = tap % 3 - 1;
        const int iy = oyA + ky, ix = oxA + kx;
        const bool v = (unsigned)iy < (unsigned)H && (unsigned)ix < (unsigned)W;
        const bf16* pa = X + ib + ((long)iy * W + ix) * Cin + q * 8;
        for (int ci = 0; ci < cpt; ++ci) {
            s8 a = v ? *(const s8*)(pa + (ci << 5)) : z8;
#pragma unroll
            for (int gi = 0; gi < 5; ++gi) {
                int g = og0 + gi;
                if (g >= og1) break;
                s8 bb = *(const s8*)(wP + ((long)(g * 9 + tap) * cpt + ci) * 512 + lofs);
                acc[gi] = __builtin_amdgcn_mfma_f32_16x16x32_bf16(a, bb, acc[gi], 0, 0, 0);
            }
        }
    }
#pragma unroll
    for (int gi = 0; gi < 5; ++gi) {
        int g = og0 + gi;
        if (g >= og1) break;
        int oc = g * 16 + n16;
        float bz = bias[oc];
        int pxl = pxb + mq * 16 + q * 4;
#pragma unroll
        for (int r = 0; r < 4; ++r) {
            float v = acc[gi][r] + bz;
            if (relu) v = v > 0.f ? v : 0.1f * v;
            int px = pxl + r;
            if (EPI == 0)
                ((bf16*)out)[((long)b * HW + px) * Cout + oc] = __float2bfloat16(v);
            else {
                v += b2f(res[((long)b * HW + px) * 192 + 96 + oc]);
                ((float*)out)[((long)b * Cout + oc) * HW + px] = v;
            }
        }
    }
}

// -------- DCNv1: group-vector bilinear sample + MFMA contraction.
// Block = 16 px of one row. Items = (px, g8, kk); each loads 12 contiguous
// channels per corner from ref in HWC bf16 (X2 ch 0..95). LDS s layout
// [px][kk*96+c]; wD packed to match. --------
__global__ __launch_bounds__(256, 4) void deform_m_k(
    const bf16* __restrict__ Xref, const bf16* __restrict__ offs,
    const bf16* __restrict__ wD, const float* __restrict__ db,
    bf16* __restrict__ X2) {
    const int H = 128, W = 128;
    __shared__ bf16 offL[16 * 144];
    __shared__ bf16 s[16][872];          // 864 + 8 pad
    int bid = blockIdx.x;
    const int band = bid & 7;            // XCD residue -> 16-row band
    int r = bid >> 3;
    const int b = r >> 7; r &= 127;
    const int rowin = r >> 3, xb = r & 7;
    const int oy = band * 16 + rowin;
    const int ox0 = xb * 16;
    const int tid = threadIdx.x;
    const long pxbase = (long)b * (H * W) + oy * W + ox0;
    // stage offsets (coalesced: lanes -> consecutive cc)
    for (int e = tid; e < 16 * 144; e += 256)
        offL[e] = offs[(pxbase + (e / 144)) * 144 + (e % 144)];
    __syncthreads();
    // phase 2: items (p, g8, kk); 12-channel vector bilinear from HWC bf16 ref
    const long refb = (long)b * (H * W);
    for (int e = tid; e < 16 * 72; e += 256) {
        int p = e / 72, rem = e % 72;
        int g8 = rem / 9, kk = rem % 9;
        int ox = ox0 + p;
        float offy = b2f(offL[p * 144 + g8 * 18 + kk * 2]);
        float offx = b2f(offL[p * 144 + g8 * 18 + kk * 2 + 1]);
        float py = (float)(oy + kk / 3 - 1) + offy;
        float px = (float)(ox + kk % 3 - 1) + offx;
        float y0f = floorf(py), x0f = floorf(px);
        float ly = py - y0f, lx = px - x0f;
        int y0 = (int)y0f, x0 = (int)x0f;
        float w00 = (1.f - ly) * (1.f - lx), w01 = (1.f - ly) * lx;
        float w10 = ly * (1.f - lx), w11 = ly * lx;
        float v[12];
#pragma unroll
        for (int j = 0; j < 12; ++j) v[j] = 0.f;
        auto corner = [&](int yy, int xx, float wgt) {
            if ((unsigned)yy < (unsigned)H && (unsigned)xx < (unsigned)W) {
                const s4* cp = (const s4*)(Xref + (refb + yy * W + xx) * 192 + g8 * 12);
                s4 c0 = cp[0], c1 = cp[1], c2 = cp[2];
#pragma unroll
                for (int j = 0; j < 4; ++j) {
                    v[j]     = fmaf(bs2f(c0[j]), wgt, v[j]);
                    v[4 + j] = fmaf(bs2f(c1[j]), wgt, v[4 + j]);
                    v[8 + j] = fmaf(bs2f(c2[j]), wgt, v[8 + j]);
                }
            }
        };
        corner(y0, x0, w00);
        corner(y0, x0 + 1, w01);
        corner(y0 + 1, x0, w10);
        corner(y0 + 1, x0 + 1, w11);
        short rr[12];
#pragma unroll
        for (int j = 0; j < 12; ++j) {
            bf16 h = __float2bfloat16(v[j]);
            rr[j] = *(short*)&h;
        }
        s4* dst = (s4*)&s[p][kk * 96 + g8 * 12];
        dst[0] = ((s4*)rr)[0];
        dst[1] = ((s4*)rr)[1];
        dst[2] = ((s4*)rr)[2];
    }
    __syncthreads();
    // phase 3: MFMA [16px x 864] x [864 x 96oc]; 6 tasks over 4 waves
    const int wave = tid >> 6, lane = tid & 63;
    const int q = lane >> 4, n16 = lane & 15;
    const f4 z4 = {0.f, 0.f, 0.f, 0.f};
    for (int g = wave; g < 6; g += 4) {
        f4 acc = z4;
        const bf16* wg = wD + (long)g * 27 * 512 + (lane << 3);
#pragma unroll 3
        for (int ci = 0; ci < 27; ++ci) {
            s8 a = *(const s8*)&s[n16][ci * 32 + q * 8];
            s8 bb = *(const s8*)(wg + ci * 512);
            acc = __builtin_amdgcn_mfma_f32_16x16x32_bf16(a, bb, acc, 0, 0, 0);
        }
        int oc = g * 16 + n16;
        float bz = db[oc];
#pragma unroll
        for (int rr2 = 0; rr2 < 4; ++rr2) {
            int p = q * 4 + rr2;           // D row = q*4 + reg
            X2[(pxbase + p) * 192 + 96 + oc] = __float2bfloat16(acc[rr2] + bz);
        }
    }
}

extern "C" void kernel_launch(void* const* d_in, const int* in_sizes, int n_in,
                              void* d_out, int out_size, void* d_ws, size_t ws_size,
                              hipStream_t stream) {
    const float* ref_fea = (const float*)d_in[0];
    const float* inp_fea = (const float*)d_in[1];
    const float* oc1_w = (const float*)d_in[2];  const float* oc1_b = (const float*)d_in[3];
    const float* oc3_w = (const float*)d_in[4];  const float* oc3_b = (const float*)d_in[5];
    const float* enc1_w = (const float*)d_in[6]; const float* enc1_b = (const float*)d_in[7];
    const float* enc2_w = (const float*)d_in[8]; const float* enc2_b = (const float*)d_in[9];
    const float* dec1_w = (const float*)d_in[10]; const float* dec1_b = (const float*)d_in[11];
    const float* dec2_w = (const float*)d_in[12]; const float* dec2_b = (const float*)d_in[13];
    const float* coff_w = (const float*)d_in[14]; const float* coff_b = (const float*)d_in[15];
    const float* dcn_w = (const float*)d_in[16];  const float* dcn_b = (const float*)d_in[17];
    const float* ref1_w = (const float*)d_in[18]; const float* ref1_b = (const float*)d_in[19];
    const float* ref2_w = (const float*)d_in[20]; const float* ref2_b = (const float*)d_in[21];

    float* out = (float*)d_out;
    float* OUTS = out;                    // out0 region as fp32 scratch (t1)
    float* S1 = (float*)d_ws;             // 12.58 MB slot
    float* S2 = S1 + N_FEA;               // 12.58 MB slot
    float* T2 = S2;                       // t2 (oc3 output) lives in S2
    float* F = S1 + N_E1;                 // q fp32 (after e1 region)
    bf16* de_hwc = (bf16*)S1;
    bf16* offs = (bf16*)S2;               // HWC [b][HW][144] (9.44 MB)
    bf16* X2 = (bf16*)S1;                 // [ref | aligned] HWC 192c
    bf16* r1 = (bf16*)S2;
    bf16* wtb = (bf16*)S2 + 4800000;      // tail at S2+9.6 MB (written after t2 consumed)
    bf16* wt_coff = wtb;                  // 124416
    bf16* wt_ref1 = wt_coff + 124416;     // 165888
    bf16* wt_ref2 = wt_ref1 + 165888;     // 82944
    bf16* wt_dcn = wt_ref2 + 82944;       // 82944 (MFMA-B pack)
    float* wdec1 = (float*)(wt_dcn + 82944);  // 82944 fp32 (dec1 quad pack)
    float* wdec2 = wdec1 + 82944;             // 82944 fp32 (dec2 quad pack)
    // scalar-weight packs for oc1/oc3 in the en/q output region (consumed
    // before enc2 overwrites it)
    float* wsc1 = out + OUT_EN;           // 165888 fp32
    float* wsc3 = wsc1 + 165888;          // 82944 fp32
    // enc weight packs in S1 tail (free until pack_hwc overwrites S1)
    float* wenc1 = S1 + 1048576;          // 82944 fp32
    float* wenc2 = wenc1 + 82944;         // 82944 fp32

    dim3 blk(256);
    auto nb = [](long n) { return dim3((unsigned)((n + 255) / 256)); };

    // ---- encoder (fp32-exact; fused split-K + bias + lrelu) ----
    wpack_sw<<<nb(165888L + 82944), blk, 0, stream>>>(oc1_w, oc3_w, wsc1, wsc3);
    // t1 = lrelu(conv([ref|inp], oc1)) -> OUTS
    conv3x3_fu<8><<<dim3(768), blk, 0, stream>>>(ref_fea, 96, 96,
                                                 inp_fea, 96, 96,
                                                 wsc1, oc1_b, OUTS, 96);
    // t2 = lrelu(conv([t1a|t1b], oc3)) -> S2
    conv3x3_fu<8><<<dim3(768), blk, 0, stream>>>(OUTS, 48, 96,
                                                 OUTS + 48 * 16384, 48, 96,
                                                 wsc3, oc3_b, T2, 96);
    wpack_enc<<<nb(82944L + 82944), blk, 0, stream>>>(enc1_w, enc2_w, wenc1, wenc2);
    // enc1: 1 px/thread, OCB=4 -> 2*24*16 = 768 blocks (3/CU); reads t2 (S2)
    conv_s2_px<4><<<dim3(768), blk, 0, stream>>>(T2, 96, 128, 128,
                                                 wenc1, enc1_b, S1, 96, 1,
                                                 nullptr, nullptr);
    wxform_all<<<nb(124416L + 165888 + 82944 + 82944), blk, 0, stream>>>(
        coff_w, ref1_w, ref2_w, dcn_w, wt_coff, wt_ref1, wt_ref2, wt_dcn);
    wpack_dec<<<nb(82944L + 82944), blk, 0, stream>>>(dec1_w, dec2_w, wdec1, wdec2);
    // enc2: 1 px/thread, OCB=2 -> 2*48*4 = 384 blocks
    conv_s2_px<2><<<dim3(384), blk, 0, stream>>>(S1, 96, 64, 64,
                                                 wenc2, enc2_b, out + OUT_EN, 96, 0,
                                                 out + OUT_Q, F);
    // ---- decoder: quad ConvT, SGPR weights ----
    // dec1: 32x32 input, OCB=2 -> 2*48*4 = 384 blocks, fp32 NCHW out
    convt_quad<2, 0><<<dim3(384), blk, 0, stream>>>(F, wdec1, dec1_b, S2, 32, 32, 1);
    // dec2: 64x64 input, OCB=4 -> 2*24*16 = 768 blocks, bf16 HWC out
    convt_quad<4, 1><<<dim3(768), blk, 0, stream>>>(S2, wdec2, dec2_b, de_hwc, 64, 64, 0);
    // ---- MFMA: offsets = conv(de) -> HWC bf16 (512-thread 8-wave blocks) ----
    mconv<0><<<dim3(512), dim3(512), 0, stream>>>(de_hwc, wt_coff, coff_b, offs, nullptr,
                                                  96, 144, 128, 128, 0);
    // ---- X2 = [ref | aligned] HWC ----
    pack_hwc<<<nb(N_FEA), blk, 0, stream>>>(ref_fea, X2, 16384, 192, 0);
    deform_m_k<<<dim3(2048), blk, 0, stream>>>(X2, offs, wt_dcn, dcn_b, X2);
    // ---- MFMA: r1 = lrelu(conv(X2, ref1)); out0 = aligned + lrelu(conv(r1, ref2)) ----
    mconv<0><<<dim3(512), dim3(512), 0, stream>>>(X2, wt_ref1, ref1_b, r1, nullptr,
                                                  192, 96, 128, 128, 1);
    mconv<3><<<dim3(512), dim3(512), 0, stream>>>(r1, wt_ref2, ref2_b, out, X2,
                                                  96, 96, 128, 128, 1);
}

// Round 13
// 780.436 us; speedup vs baseline: 1.0497x; 1.0497x over previous
//
#include <hip/hip_runtime.h>
#include <hip/hip_bf16.h>

typedef __hip_bfloat16 bf16;
typedef __attribute__((ext_vector_type(8))) short s8;   // 8 x bf16 MFMA A/B frag
typedef __attribute__((ext_vector_type(4))) short s4;   // 4 x bf16 (8B)
typedef __attribute__((ext_vector_type(4))) float f4;   // MFMA C/D frag

#define N_FEA   3145728   // 2*96*128*128
#define N_EN    196608    // 2*96*32*32
#define N_E1    786432    // 2*96*64*64
#define OUT_EN  3145728
#define OUT_Q   3342336

__device__ __forceinline__ float b2f(bf16 v) { return __bfloat162float(v); }
__device__ __forceinline__ float bs2f(short v) {
    union { unsigned u; float f; } x; x.u = ((unsigned)(unsigned short)v) << 16; return x.f;
}

// -------- pack oc1/oc3 weights for scalar-load conv: [ks][ocg][c][kx][o][ky] --------
__global__ void wpack_sw(const float* __restrict__ w1, const float* __restrict__ w3,
                         float* __restrict__ o1, float* __restrict__ o3) {
    long i = (long)blockIdx.x * 256 + threadIdx.x;
    const long n1 = 2L * 12 * 96 * 72;   // 165888
    if (i < n1) {
        int ky = (int)(i % 3); long t = i / 3;
        int o = (int)(t % 8); t /= 8;
        int kx = (int)(t % 3); t /= 3;
        int c = (int)(t % 96); t /= 96;
        int ocg = (int)(t % 12); int ks = (int)(t / 12);
        o1[i] = w1[((long)(ocg * 8 + o) * 192 + ks * 96 + c) * 9 + ky * 3 + kx];
        return;
    }
    i -= n1;
    const long n3 = 2L * 12 * 48 * 72;   // 82944
    if (i < n3) {
        int ky = (int)(i % 3); long t = i / 3;
        int o = (int)(t % 8); t /= 8;
        int kx = (int)(t % 3); t /= 3;
        int c = (int)(t % 48); t /= 48;
        int ocg = (int)(t % 12); int ks = (int)(t / 12);
        o3[i] = w3[((long)(ocg * 8 + o) * 96 + ks * 48 + c) * 9 + ky * 3 + kx];
    }
}

// -------- pack enc1/enc2 weights for stride-2 scalar conv: [ocg][c][o][ky*3+kx] ----
__global__ void wpack_enc(const float* __restrict__ w1, const float* __restrict__ w2,
                          float* __restrict__ o1, float* __restrict__ o2) {
    long i = (long)blockIdx.x * 256 + threadIdx.x;
    const long n1 = 24L * 96 * 4 * 9;    // 82944 (OCB=4)
    if (i < n1) {
        int k = (int)(i % 9);
        int o = (int)((i / 9) % 4);
        int c = (int)((i / 36) % 96);
        int ocg = (int)(i / (36 * 96));
        o1[i] = w1[((long)(ocg * 4 + o) * 96 + c) * 9 + k];
        return;
    }
    i -= n1;
    const long n2 = 48L * 96 * 2 * 9;    // 82944 (OCB=2)
    if (i < n2) {
        int k = (int)(i % 9);
        int o = (int)((i / 9) % 2);
        int c = (int)((i / 18) % 96);
        int ocg = (int)(i / (18 * 96));
        o2[i] = w2[((long)(ocg * 2 + o) * 96 + c) * 9 + k];
    }
}

// -------- pack dec1/dec2 (ConvT, w=[Cin][Cout][3][3]) -> [ocg][c][o][ky*3+kx] -----
__global__ void wpack_dec(const float* __restrict__ w1, const float* __restrict__ w2,
                          float* __restrict__ o1, float* __restrict__ o2) {
    long i = (long)blockIdx.x * 256 + threadIdx.x;
    const long n1 = 48L * 96 * 2 * 9;    // 82944 (dec1, OCB=2)
    if (i < n1) {
        int k = (int)(i % 9);
        int o = (int)((i / 9) % 2);
        int c = (int)((i / 18) % 96);
        int ocg = (int)(i / (18 * 96));
        o1[i] = w1[((long)c * 96 + ocg * 2 + o) * 9 + k];
        return;
    }
    i -= n1;
    const long n2 = 24L * 96 * 4 * 9;    // 82944 (dec2, OCB=4)
    if (i < n2) {
        int k = (int)(i % 9);
        int o = (int)((i / 9) % 4);
        int c = (int)((i / 36) % 96);
        int ocg = (int)(i / (36 * 96));
        o2[i] = w2[((long)c * 96 + ocg * 4 + o) * 9 + k];
    }
}

// ---- split-K stride-1 direct conv, 128x128, LDS-broadcast weights ----
// Weights staged ONCE per block into LDS (straight copy of the pre-packed
// [c][kx][o][ky] buffer; single barrier), then read as conflict-free
// broadcast ds_read_b128 — removes the per-wave scalar-cache re-stream
// stall. Thread = 1 col x 4 rows; grid 768. FMA order per output
// (c asc; kx, o, ky, j) identical to prior rounds (bit-exact).
template <int OCB>
__global__ __launch_bounds__(256) void conv3x3_sw(
    const float* __restrict__ inA, int cA, int bstrA,
    const float* __restrict__ inB, int cB, int bstrB,
    const float* __restrict__ wsc,
    float* __restrict__ P0, float* __restrict__ P1, int Cout) {
    const int H = 128, W = 128;
    const int NOC = Cout / OCB;          // 12
    int bid = blockIdx.x;
    const int ks = bid & 1;
    int r = bid >> 1;
    const int strip = r & 15; r >>= 4;
    const int ocg = r % NOC;
    const int b = r / NOC;
    const float* in = ks ? inB : inA;
    const int cN = ks ? cB : cA;
    const int bstr = ks ? bstrB : bstrA;
    float* P = ks ? P1 : P0;
    const float* wq0 = wsc + ((long)(ks * NOC + ocg) * cN) * 72;

    __shared__ __align__(16) float wl[96 * 72];   // <= 27.6 KB
    for (int i = threadIdx.x; i < cN * 72; i += 256) wl[i] = wq0[i];
    __syncthreads();

    const int ox = threadIdx.x & 127;
    const int ry = (threadIdx.x >> 7) << 2;   // 0 or 4 (wave-uniform)
    const int oy0 = strip * 8 + ry;
    const int iyb = oy0 - 1;

    bool vy[6];
#pragma unroll
    for (int j = 0; j < 6; ++j) vy[j] = (unsigned)(iyb + j) < (unsigned)H;

    float acc[OCB][4];
#pragma unroll
    for (int o = 0; o < OCB; ++o)
#pragma unroll
        for (int j = 0; j < 4; ++j) acc[o][j] = 0.f;

    const float* pc = in + (long)b * bstr * H * W + (long)iyb * W;
    for (int c = 0; c < cN; ++c) {
        const float* wq = &wl[c * 72];
#pragma unroll
        for (int kx = 0; kx < 3; ++kx) {
            const int ix = ox + kx - 1;
            const bool vx = (unsigned)ix < (unsigned)W;
            float rv[6];
#pragma unroll
            for (int j = 0; j < 6; ++j)
                rv[j] = (vx && vy[j]) ? pc[j * W + ix] : 0.f;
#pragma unroll
            for (int o = 0; o < OCB; ++o) {
#pragma unroll
                for (int ky = 0; ky < 3; ++ky) {
                    float wz = wq[kx * 24 + o * 3 + ky];   // LDS broadcast
#pragma unroll
                    for (int j = 0; j < 4; ++j)
                        acc[o][j] = fmaf(rv[j + ky], wz, acc[o][j]);
                }
            }
        }
        pc += (long)H * W;
    }
#pragma unroll
    for (int o = 0; o < OCB; ++o) {
        long base = (((long)b * Cout + ocg * OCB + o) * H + oy0) * W + ox;
#pragma unroll
        for (int j = 0; j < 4; ++j) P[base + (long)j * W] = acc[o][j];
    }
}

// out = lrelu(bias + p0 + p1)
__global__ void fuse_add_k(const float* __restrict__ p0, const float* __restrict__ p1,
                           const float* __restrict__ bias, float* __restrict__ out) {
    long idx = (long)blockIdx.x * 256 + threadIdx.x;
    if (idx >= (long)N_FEA) return;
    int oc = (int)((idx >> 14) % 96);
    float a = bias[oc] + p0[idx] + p1[idx];
    out[idx] = a > 0.f ? a : 0.1f * a;
}

// ---- stride-2 direct conv, SGPR weights, no LDS, 1 output px/thread ----
template <int OCB>
__global__ __launch_bounds__(256) void conv_s2_px(
    const float* __restrict__ in, int Cin, int Hin, int Win,
    const float* __restrict__ wsc, const float* __restrict__ bias,
    float* __restrict__ out, int Cout, int relu,
    float* __restrict__ qq, float* __restrict__ qf2) {
    const int Hout = Hin >> 1, Wout = Win >> 1;
    const int rpb = 256 / Wout;              // rows per block (1 px/thread)
    const int strips = Hout / rpb;
    int bid = blockIdx.x;
    const int strip = bid % strips; bid /= strips;
    const int NOC = Cout / OCB;
    const int ocg = bid % NOC;
    const int b = bid / NOC;
    const int tid = threadIdx.x;
    const int ox = tid % Wout;
    const int oy = strip * rpb + tid / Wout;
    const int iy0 = oy * 2 - 1, ix0 = ox * 2 - 1;
    const float* wq0 = wsc + (long)(ocg * Cin) * (OCB * 9);

    float acc[OCB];
#pragma unroll
    for (int o = 0; o < OCB; ++o) acc[o] = bias[ocg * OCB + o];
    const bool vx0 = ix0 >= 0;               // only left col / top row can be OOB
    const bool vy0 = iy0 >= 0;

    const float* pc = in + (long)b * Cin * Hin * Win + (long)iy0 * Win + ix0;
    for (int c = 0; c < Cin; ++c) {
        float rv[3][3];
#pragma unroll
        for (int jr = 0; jr < 3; ++jr) {
            const float* row = pc + jr * Win;
            const bool vr = jr ? true : vy0;
            rv[jr][0] = (vr && vx0) ? row[0] : 0.f;
            rv[jr][1] = vr ? row[1] : 0.f;
            rv[jr][2] = vr ? row[2] : 0.f;
        }
        const float* wq = wq0 + c * (OCB * 9);
#pragma unroll
        for (int o = 0; o < OCB; ++o)
#pragma unroll
            for (int ky = 0; ky < 3; ++ky)
#pragma unroll
                for (int kx = 0; kx < 3; ++kx)
                    acc[o] = fmaf(rv[ky][kx], wq[o * 9 + ky * 3 + kx], acc[o]);
        pc += (long)Hin * Win;
    }
#pragma unroll
    for (int o = 0; o < OCB; ++o) {
        long idx = (((long)b * Cout + ocg * OCB + o) * Hout + oy) * Wout + ox;
        float a = acc[o];
        if (relu) a = a > 0.f ? a : 0.1f * a;
        out[idx] = a;
        if (qq) {
            float qv = rintf(a);
            qq[idx] = qv;
            qf2[idx] = qv;
        }
    }
}

// ---- ConvTranspose2d(96->96,k3,s2,p1,op1): 2x2 output quad per thread, ----
// SGPR weights [ocg][c][o][ky*3+kx], 4 coalesced loads/c serve all 9 taps.
template <int OCB, int HWC>
__global__ __launch_bounds__(256) void convt_quad(
    const float* __restrict__ in, const float* __restrict__ wsc,
    const float* __restrict__ bias, void* __restrict__ out,
    int Hin, int Win, int relu) {
    const int C = 96;
    const int Hout = 2 * Hin, Wout = 2 * Win;
    const int strips = (Hin * Win) / 256;
    int bid = blockIdx.x;
    const int strip = bid % strips; bid /= strips;
    const int NOC = C / OCB;
    const int ocg = bid % NOC;
    const int b = bid / NOC;
    const int idx = strip * 256 + threadIdx.x;
    const int iy = idx / Win, ix = idx % Win;
    const bool vr = (ix + 1) < Win, vd = (iy + 1) < Hin;
    const float* wq0 = wsc + (long)(ocg * C) * (OCB * 9);

    float acc[OCB][4];
#pragma unroll
    for (int o = 0; o < OCB; ++o) {
        float bz = bias[ocg * OCB + o];
#pragma unroll
        for (int j = 0; j < 4; ++j) acc[o][j] = bz;
    }
    const float* pc = in + (long)b * C * Hin * Win + (long)iy * Win + ix;
    for (int c = 0; c < C; ++c) {
        float i00 = pc[0];
        float i01 = vr ? pc[1] : 0.f;
        float i10 = vd ? pc[Win] : 0.f;
        float i11 = (vr && vd) ? pc[Win + 1] : 0.f;
        const float* wq = wq0 + c * (OCB * 9);
#pragma unroll
        for (int o = 0; o < OCB; ++o) {
            const float* w = wq + o * 9;
            acc[o][0] = fmaf(i00, w[4], acc[o][0]);
            acc[o][1] = fmaf(i01, w[3], fmaf(i00, w[5], acc[o][1]));
            acc[o][2] = fmaf(i10, w[1], fmaf(i00, w[7], acc[o][2]));
            acc[o][3] = fmaf(i11, w[0],
                        fmaf(i10, w[2],
                        fmaf(i01, w[6],
                        fmaf(i00, w[8], acc[o][3]))));
        }
        pc += (long)Hin * Win;
    }
#pragma unroll
    for (int o = 0; o < OCB; ++o) {
        int oc = ocg * OCB + o;
#pragma unroll
        for (int j = 0; j < 4; ++j) {
            float a = acc[o][j];
            if (relu) a = a > 0.f ? a : 0.1f * a;
            int oy = 2 * iy + (j >> 1), ox2 = 2 * ix + (j & 1);
            if (HWC)
                ((bf16*)out)[((long)b * Hout * Wout + (long)oy * Wout + ox2) * 96 + oc] =
                    __float2bfloat16(a);
            else
                ((float*)out)[(((long)b * C + oc) * Hout + oy) * Wout + ox2] = a;
        }
    }
}

// -------- combined weight transforms: 3x MFMA-B pack + dcn MFMA-B pack ------
__device__ __forceinline__ void packw(const float* __restrict__ w, bf16* __restrict__ wP,
                                      int Cin, int swap, long i) {
    const int cpt = Cin >> 5;
    int e = (int)(i & 7);
    int n16 = (int)((i >> 3) & 15);
    int q = (int)((i >> 7) & 3);
    long t = i >> 9;
    int ci = (int)(t % cpt); t /= cpt;
    int tap = (int)(t % 9);
    int g = (int)(t / 9);
    int oc = g * 16 + n16;
    int c = ci * 32 + q * 8 + e;
    int cs = swap ? (c + Cin / 2) % Cin : c;
    wP[i] = __float2bfloat16(w[((long)oc * Cin + cs) * 9 + tap]);
}
__global__ void wxform_all(const float* __restrict__ coffw, const float* __restrict__ ref1w,
                           const float* __restrict__ ref2w, const float* __restrict__ dcnw,
                           bf16* __restrict__ p_coff, bf16* __restrict__ p_ref1,
                           bf16* __restrict__ p_ref2, bf16* __restrict__ p_dcn) {
    const long n1 = 124416, n2 = 165888, n3 = 82944, n4 = 82944;
    long i = (long)blockIdx.x * 256 + threadIdx.x;
    if (i < n1) { packw(coffw, p_coff, 96, 0, i); return; }
    i -= n1;
    if (i < n2) { packw(ref1w, p_ref1, 192, 1, i); return; }
    i -= n2;
    if (i < n3) { packw(ref2w, p_ref2, 96, 0, i); return; }
    i -= n3;
    if (i < n4) {
        // dcn: K=864 GEMM-B pack [g][ci][lane][8]; k' = ci*32+q*8+e with
        // K-ordering k' = kk*96 + c  (matches deform's [px][kk][c] LDS layout)
        int e = (int)(i & 7);
        int n16 = (int)((i >> 3) & 15);
        int q = (int)((i >> 7) & 3);
        long t = i >> 9;
        int ci = (int)(t % 27);
        int g = (int)(t / 27);
        int kp = ci * 32 + q * 8 + e;     // k' in [0,864)
        int c = kp % 96, kk = kp / 96;
        p_dcn[i] = __float2bfloat16(dcnw[(long)(g * 16 + n16) * 864 + c * 9 + kk]);
    }
}

// -------- pack fp32 NCHW (96 ch) -> bf16 HWC [b][y][x][Cs] at channel offset --------
__global__ void pack_hwc(const float* __restrict__ src, bf16* __restrict__ dst,
                         int HW, int Cs, int coff) {
    long i = (long)blockIdx.x * 256 + threadIdx.x;
    if (i >= 2L * 96 * HW) return;
    int px = (int)(i % HW);
    long t = i / HW;
    int c = (int)(t % 96);
    int b = (int)(t / 96);
    dst[((long)b * HW + px) * Cs + coff + c] = __float2bfloat16(src[i]);
}

// ----------------- MFMA implicit-GEMM 3x3 conv (stride 1, 128x128) -----------------
template <int EPI>
__global__ __launch_bounds__(256) void mconv(
    const bf16* __restrict__ X, const bf16* __restrict__ wP,
    const float* __restrict__ bias, void* __restrict__ out,
    const bf16* __restrict__ res,
    int Cin, int Cout, int H, int W, int relu) {
    const int HW = H * W;
    const int NG = Cout >> 4, split = (NG + 1) >> 1;
    int bid = blockIdx.x;
    const int nb = HW >> 6;
    const int pxb = (bid % nb) << 6;
    const int b = bid / nb;
    const int wave = threadIdx.x >> 6, lane = threadIdx.x & 63;
    const int mt = (wave >> 1) << 5;
    const int og0 = (wave & 1) ? split : 0;
    const int og1 = (wave & 1) ? NG : split;
    const int q = lane >> 4, n16 = lane & 15;
    const int pA0 = pxb + mt + n16, pA1 = pA0 + 16;
    const int oy0 = pA0 / W, ox0 = pA0 % W;
    const int oy1 = pA1 / W, ox1 = pA1 % W;
    const long ib = (long)b * HW * Cin;
    f4 acc0[5], acc1[5];
    const f4 z4 = {0.f, 0.f, 0.f, 0.f};
#pragma unroll
    for (int g = 0; g < 5; ++g) { acc0[g] = z4; acc1[g] = z4; }
    const s8 z8 = {0, 0, 0, 0, 0, 0, 0, 0};
    const int cpt = Cin >> 5;
    const int lofs = lane << 3;
    for (int tap = 0; tap < 9; ++tap) {
        const int ky = tap / 3 - 1, kx = tap % 3 - 1;
        const int iy0 = oy0 + ky, ix0 = ox0 + kx;
        const int iy1 = oy1 + ky, ix1 = ox1 + kx;
        const bool v0 = (unsigned)iy0 < (unsigned)H && (unsigned)ix0 < (unsigned)W;
        const bool v1 = (unsigned)iy1 < (unsigned)H && (unsigned)ix1 < (unsigned)W;
        const bf16* pa0 = X + ib + ((long)iy0 * W + ix0) * Cin + q * 8;
        const bf16* pa1 = X + ib + ((long)iy1 * W + ix1) * Cin + q * 8;
        for (int ci = 0; ci < cpt; ++ci) {
            const int c0 = ci << 5;
            s8 a0 = v0 ? *(const s8*)(pa0 + c0) : z8;
            s8 a1 = v1 ? *(const s8*)(pa1 + c0) : z8;
#pragma unroll
            for (int gi = 0; gi < 5; ++gi) {
                int g = og0 + gi;
                if (g >= og1) break;
                s8 bb = *(const s8*)(wP + ((long)(g * 9 + tap) * cpt + ci) * 512 + lofs);
                acc0[gi] = __builtin_amdgcn_mfma_f32_16x16x32_bf16(a0, bb, acc0[gi], 0, 0, 0);
                acc1[gi] = __builtin_amdgcn_mfma_f32_16x16x32_bf16(a1, bb, acc1[gi], 0, 0, 0);
            }
        }
    }
#pragma unroll
    for (int gi = 0; gi < 5; ++gi) {
        int g = og0 + gi;
        if (g >= og1) break;
        int oc = g * 16 + n16;
        float bz = bias[oc];
#pragma unroll
        for (int t = 0; t < 2; ++t) {
            f4 a = t ? acc1[gi] : acc0[gi];
            int pxl = pxb + mt + t * 16 + q * 4;
#pragma unroll
            for (int r = 0; r < 4; ++r) {
                float v = a[r] + bz;
                if (relu) v = v > 0.f ? v : 0.1f * v;
                int px = pxl + r;
                if (EPI == 0)
                    ((bf16*)out)[((long)b * HW + px) * Cout + oc] = __float2bfloat16(v);
                else {
                    v += b2f(res[((long)b * HW + px) * 192 + 96 + oc]);
                    ((float*)out)[((long)b * Cout + oc) * HW + px] = v;
                }
            }
        }
    }
}

// -------- DCNv1: group-vector bilinear sample + MFMA contraction.
// Block = 16 px of one row. Items = (px, g8, kk); each loads 12 contiguous
// channels per corner from ref in HWC bf16 (X2 ch 0..95). LDS s layout
// [px][kk*96+c]; wD packed to match. --------
__global__ __launch_bounds__(256, 4) void deform_m_k(
    const bf16* __restrict__ Xref, const bf16* __restrict__ offs,
    const bf16* __restrict__ wD, const float* __restrict__ db,
    bf16* __restrict__ X2) {
    const int H = 128, W = 128;
    __shared__ bf16 offL[16 * 144];
    __shared__ bf16 s[16][872];          // 864 + 8 pad
    int bid = blockIdx.x;
    const int band = bid & 7;            // XCD residue -> 16-row band
    int r = bid >> 3;
    const int b = r >> 7; r &= 127;
    const int rowin = r >> 3, xb = r & 7;
    const int oy = band * 16 + rowin;
    const int ox0 = xb * 16;
    const int tid = threadIdx.x;
    const long pxbase = (long)b * (H * W) + oy * W + ox0;
    // stage offsets (coalesced: lanes -> consecutive cc)
    for (int e = tid; e < 16 * 144; e += 256)
        offL[e] = offs[(pxbase + (e / 144)) * 144 + (e % 144)];
    __syncthreads();
    // phase 2: items (p, g8, kk); 12-channel vector bilinear from HWC bf16 ref
    const long refb = (long)b * (H * W);
    for (int e = tid; e < 16 * 72; e += 256) {
        int p = e / 72, rem = e % 72;
        int g8 = rem / 9, kk = rem % 9;
        int ox = ox0 + p;
        float offy = b2f(offL[p * 144 + g8 * 18 + kk * 2]);
        float offx = b2f(offL[p * 144 + g8 * 18 + kk * 2 + 1]);
        float py = (float)(oy + kk / 3 - 1) + offy;
        float px = (float)(ox + kk % 3 - 1) + offx;
        float y0f = floorf(py), x0f = floorf(px);
        float ly = py - y0f, lx = px - x0f;
        int y0 = (int)y0f, x0 = (int)x0f;
        float w00 = (1.f - ly) * (1.f - lx), w01 = (1.f - ly) * lx;
        float w10 = ly * (1.f - lx), w11 = ly * lx;
        float v[12];
#pragma unroll
        for (int j = 0; j < 12; ++j) v[j] = 0.f;
        auto corner = [&](int yy, int xx, float wgt) {
            if ((unsigned)yy < (unsigned)H && (unsigned)xx < (unsigned)W) {
                const s4* cp = (const s4*)(Xref + (refb + yy * W + xx) * 192 + g8 * 12);
                s4 c0 = cp[0], c1 = cp[1], c2 = cp[2];
#pragma unroll
                for (int j = 0; j < 4; ++j) {
                    v[j]     = fmaf(bs2f(c0[j]), wgt, v[j]);
                    v[4 + j] = fmaf(bs2f(c1[j]), wgt, v[4 + j]);
                    v[8 + j] = fmaf(bs2f(c2[j]), wgt, v[8 + j]);
                }
            }
        };
        corner(y0, x0, w00);
        corner(y0, x0 + 1, w01);
        corner(y0 + 1, x0, w10);
        corner(y0 + 1, x0 + 1, w11);
        short rr[12];
#pragma unroll
        for (int j = 0; j < 12; ++j) {
            bf16 h = __float2bfloat16(v[j]);
            rr[j] = *(short*)&h;
        }
        s4* dst = (s4*)&s[p][kk * 96 + g8 * 12];
        dst[0] = ((s4*)rr)[0];
        dst[1] = ((s4*)rr)[1];
        dst[2] = ((s4*)rr)[2];
    }
    __syncthreads();
    // phase 3: MFMA [16px x 864] x [864 x 96oc]; 6 tasks over 4 waves
    const int wave = tid >> 6, lane = tid & 63;
    const int q = lane >> 4, n16 = lane & 15;
    const f4 z4 = {0.f, 0.f, 0.f, 0.f};
    for (int g = wave; g < 6; g += 4) {
        f4 acc = z4;
        const bf16* wg = wD + (long)g * 27 * 512 + (lane << 3);
#pragma unroll 3
        for (int ci = 0; ci < 27; ++ci) {
            s8 a = *(const s8*)&s[n16][ci * 32 + q * 8];
            s8 bb = *(const s8*)(wg + ci * 512);
            acc = __builtin_amdgcn_mfma_f32_16x16x32_bf16(a, bb, acc, 0, 0, 0);
        }
        int oc = g * 16 + n16;
        float bz = db[oc];
#pragma unroll
        for (int rr2 = 0; rr2 < 4; ++rr2) {
            int p = q * 4 + rr2;           // D row = q*4 + reg
            X2[(pxbase + p) * 192 + 96 + oc] = __float2bfloat16(acc[rr2] + bz);
        }
    }
}

extern "C" void kernel_launch(void* const* d_in, const int* in_sizes, int n_in,
                              void* d_out, int out_size, void* d_ws, size_t ws_size,
                              hipStream_t stream) {
    const float* ref_fea = (const float*)d_in[0];
    const float* inp_fea = (const float*)d_in[1];
    const float* oc1_w = (const float*)d_in[2];  const float* oc1_b = (const float*)d_in[3];
    const float* oc3_w = (const float*)d_in[4];  const float* oc3_b = (const float*)d_in[5];
    const float* enc1_w = (const float*)d_in[6]; const float* enc1_b = (const float*)d_in[7];
    const float* enc2_w = (const float*)d_in[8]; const float* enc2_b = (const float*)d_in[9];
    const float* dec1_w = (const float*)d_in[10]; const float* dec1_b = (const float*)d_in[11];
    const float* dec2_w = (const float*)d_in[12]; const float* dec2_b = (const float*)d_in[13];
    const float* coff_w = (const float*)d_in[14]; const float* coff_b = (const float*)d_in[15];
    const float* dcn_w = (const float*)d_in[16];  const float* dcn_b = (const float*)d_in[17];
    const float* ref1_w = (const float*)d_in[18]; const float* ref1_b = (const float*)d_in[19];
    const float* ref2_w = (const float*)d_in[20]; const float* ref2_b = (const float*)d_in[21];

    float* out = (float*)d_out;
    float* OUTS = out;                    // out0 region as fp32 scratch (t1/t2)
    float* S1 = (float*)d_ws;             // 12.58 MB slot
    float* S2 = S1 + N_FEA;               // 12.58 MB slot
    float* F = S1 + N_E1;                 // q fp32 (after e1 region)
    bf16* de_hwc = (bf16*)S1;
    bf16* offs = (bf16*)S2;               // HWC [b][HW][144] (9.44 MB)
    bf16* X2 = (bf16*)S1;                 // [ref | aligned] HWC 192c
    bf16* r1 = (bf16*)S2;
    bf16* wtb = (bf16*)S2 + 4800000;      // tail at S2+9.6 MB
    bf16* wt_coff = wtb;                  // 124416
    bf16* wt_ref1 = wt_coff + 124416;     // 165888
    bf16* wt_ref2 = wt_ref1 + 165888;     // 82944
    bf16* wt_dcn = wt_ref2 + 82944;       // 82944 (MFMA-B pack)
    float* wdec1 = (float*)(wt_dcn + 82944);  // 82944 fp32 (dec1 quad pack)
    float* wdec2 = wdec1 + 82944;             // 82944 fp32 (dec2 quad pack)
    // scalar-weight packs for oc1/oc3 in the en/q output region (consumed
    // before enc2 overwrites it)
    float* wsc1 = out + OUT_EN;           // 165888 fp32
    float* wsc3 = wsc1 + 165888;          // 82944 fp32
    // enc weight packs in S1 tail (free after oc3 fuse; overwritten by X2
    // only after enc2 completes)
    float* wenc1 = S1 + 1048576;          // 82944 fp32
    float* wenc2 = wenc1 + 82944;         // 82944 fp32

    dim3 blk(256);
    auto nb = [](long n) { return dim3((unsigned)((n + 255) / 256)); };

    // ---- encoder (fp32-exact; split-K + LDS-broadcast weights) ----
    wpack_sw<<<nb(165888L + 82944), blk, 0, stream>>>(oc1_w, oc3_w, wsc1, wsc3);
    conv3x3_sw<8><<<dim3(768), blk, 0, stream>>>(ref_fea, 96, 96,
                                                 inp_fea, 96, 96,
                                                 wsc1, S1, S2, 96);
    fuse_add_k<<<nb(N_FEA), blk, 0, stream>>>(S1, S2, oc1_b, OUTS);
    conv3x3_sw<8><<<dim3(768), blk, 0, stream>>>(OUTS, 48, 96,
                                                 OUTS + 48 * 16384, 48, 96,
                                                 wsc3, S1, S2, 96);
    fuse_add_k<<<nb(N_FEA), blk, 0, stream>>>(S1, S2, oc3_b, OUTS);
    wpack_enc<<<nb(82944L + 82944), blk, 0, stream>>>(enc1_w, enc2_w, wenc1, wenc2);
    // enc1: 1 px/thread, OCB=4 -> 2*24*16 = 768 blocks (3/CU)
    conv_s2_px<4><<<dim3(768), blk, 0, stream>>>(OUTS, 96, 128, 128,
                                                 wenc1, enc1_b, S1, 96, 1,
                                                 nullptr, nullptr);
    wxform_all<<<nb(124416L + 165888 + 82944 + 82944), blk, 0, stream>>>(
        coff_w, ref1_w, ref2_w, dcn_w, wt_coff, wt_ref1, wt_ref2, wt_dcn);
    wpack_dec<<<nb(82944L + 82944), blk, 0, stream>>>(dec1_w, dec2_w, wdec1, wdec2);
    // enc2: 1 px/thread, OCB=2 -> 2*48*4 = 384 blocks
    conv_s2_px<2><<<dim3(384), blk, 0, stream>>>(S1, 96, 64, 64,
                                                 wenc2, enc2_b, out + OUT_EN, 96, 0,
                                                 out + OUT_Q, F);
    // ---- decoder: quad ConvT, SGPR weights ----
    // dec1: 32x32 input, OCB=2 -> 2*48*4 = 384 blocks, fp32 NCHW out
    convt_quad<2, 0><<<dim3(384), blk, 0, stream>>>(F, wdec1, dec1_b, S2, 32, 32, 1);
    // dec2: 64x64 input, OCB=4 -> 2*24*16 = 768 blocks, bf16 HWC out
    convt_quad<4, 1><<<dim3(768), blk, 0, stream>>>(S2, wdec2, dec2_b, de_hwc, 64, 64, 0);
    // ---- MFMA: offsets = conv(de) -> HWC bf16 ----
    mconv<0><<<dim3(512), blk, 0, stream>>>(de_hwc, wt_coff, coff_b, offs, nullptr,
                                            96, 144, 128, 128, 0);
    // ---- X2 = [ref | aligned] HWC ----
    pack_hwc<<<nb(N_FEA), blk, 0, stream>>>(ref_fea, X2, 16384, 192, 0);
    deform_m_k<<<dim3(2048), blk, 0, stream>>>(X2, offs, wt_dcn, dcn_b, X2);
    // ---- MFMA: r1 = lrelu(conv(X2, ref1)); out0 = aligned + lrelu(conv(r1, ref2)) ----
    mconv<0><<<dim3(512), blk, 0, stream>>>(X2, wt_ref1, ref1_b, r1, nullptr,
                                            192, 96, 128, 128, 1);
    mconv<3><<<dim3(512), blk, 0, stream>>>(r1, wt_ref2, ref2_b, out, X2,
                                            96, 96, 128, 128, 1);
}

// Round 14
// 760.616 us; speedup vs baseline: 1.0770x; 1.0261x over previous
//
#include <hip/hip_runtime.h>
#include <hip/hip_bf16.h>

typedef __hip_bfloat16 bf16;
typedef __attribute__((ext_vector_type(8))) short s8;   // 8 x bf16 MFMA A/B frag
typedef __attribute__((ext_vector_type(4))) short s4;   // 4 x bf16 (8B)
typedef __attribute__((ext_vector_type(4))) float f4;   // MFMA C/D frag

#define N_FEA   3145728   // 2*96*128*128
#define N_EN    196608    // 2*96*32*32
#define N_E1    786432    // 2*96*64*64
#define OUT_EN  3145728
#define OUT_Q   3342336

__device__ __forceinline__ float b2f(bf16 v) { return __bfloat162float(v); }
__device__ __forceinline__ float bs2f(short v) {
    union { unsigned u; float f; } x; x.u = ((unsigned)(unsigned short)v) << 16; return x.f;
}

// -------- pack oc1/oc3 weights for scalar-load conv: [ks][ocg][c][kx][o][ky] --------
__global__ void wpack_sw(const float* __restrict__ w1, const float* __restrict__ w3,
                         float* __restrict__ o1, float* __restrict__ o3) {
    long i = (long)blockIdx.x * 256 + threadIdx.x;
    const long n1 = 2L * 12 * 96 * 72;   // 165888
    if (i < n1) {
        int ky = (int)(i % 3); long t = i / 3;
        int o = (int)(t % 8); t /= 8;
        int kx = (int)(t % 3); t /= 3;
        int c = (int)(t % 96); t /= 96;
        int ocg = (int)(t % 12); int ks = (int)(t / 12);
        o1[i] = w1[((long)(ocg * 8 + o) * 192 + ks * 96 + c) * 9 + ky * 3 + kx];
        return;
    }
    i -= n1;
    const long n3 = 2L * 12 * 48 * 72;   // 82944
    if (i < n3) {
        int ky = (int)(i % 3); long t = i / 3;
        int o = (int)(t % 8); t /= 8;
        int kx = (int)(t % 3); t /= 3;
        int c = (int)(t % 48); t /= 48;
        int ocg = (int)(t % 12); int ks = (int)(t / 12);
        o3[i] = w3[((long)(ocg * 8 + o) * 96 + ks * 48 + c) * 9 + ky * 3 + kx];
    }
}

// -------- pack enc1/enc2 weights for stride-2 scalar conv: [ocg][c][o][ky*3+kx] ----
__global__ void wpack_enc(const float* __restrict__ w1, const float* __restrict__ w2,
                          float* __restrict__ o1, float* __restrict__ o2) {
    long i = (long)blockIdx.x * 256 + threadIdx.x;
    const long n1 = 24L * 96 * 4 * 9;    // 82944 (OCB=4)
    if (i < n1) {
        int k = (int)(i % 9);
        int o = (int)((i / 9) % 4);
        int c = (int)((i / 36) % 96);
        int ocg = (int)(i / (36 * 96));
        o1[i] = w1[((long)(ocg * 4 + o) * 96 + c) * 9 + k];
        return;
    }
    i -= n1;
    const long n2 = 48L * 96 * 2 * 9;    // 82944 (OCB=2)
    if (i < n2) {
        int k = (int)(i % 9);
        int o = (int)((i / 9) % 2);
        int c = (int)((i / 18) % 96);
        int ocg = (int)(i / (18 * 96));
        o2[i] = w2[((long)(ocg * 2 + o) * 96 + c) * 9 + k];
    }
}

// -------- pack dec1/dec2 (ConvT, w=[Cin][Cout][3][3]) -> [ocg][c][o][ky*3+kx] -----
__global__ void wpack_dec(const float* __restrict__ w1, const float* __restrict__ w2,
                          float* __restrict__ o1, float* __restrict__ o2) {
    long i = (long)blockIdx.x * 256 + threadIdx.x;
    const long n1 = 48L * 96 * 2 * 9;    // 82944 (dec1, OCB=2)
    if (i < n1) {
        int k = (int)(i % 9);
        int o = (int)((i / 9) % 2);
        int c = (int)((i / 18) % 96);
        int ocg = (int)(i / (18 * 96));
        o1[i] = w1[((long)c * 96 + ocg * 2 + o) * 9 + k];
        return;
    }
    i -= n1;
    const long n2 = 24L * 96 * 4 * 9;    // 82944 (dec2, OCB=4)
    if (i < n2) {
        int k = (int)(i % 9);
        int o = (int)((i / 9) % 4);
        int c = (int)((i / 36) % 96);
        int ocg = (int)(i / (36 * 96));
        o2[i] = w2[((long)c * 96 + ocg * 4 + o) * 9 + k];
    }
}

// ---- split-K stride-1 direct conv, 128x128, SGPR weights, no LDS, no barriers ----
// (r9 form — best measured; VMEM-wait floor ~60% VALUBusy at 170us)
template <int OCB>
__global__ __launch_bounds__(256) void conv3x3_sw(
    const float* __restrict__ inA, int cA, int bstrA,
    const float* __restrict__ inB, int cB, int bstrB,
    const float* __restrict__ wsc,
    float* __restrict__ P0, float* __restrict__ P1, int Cout) {
    const int H = 128, W = 128;
    const int NOC = Cout / OCB;          // 12
    int bid = blockIdx.x;
    const int ks = bid & 1;
    int r = bid >> 1;
    const int strip = r & 15; r >>= 4;
    const int ocg = r % NOC;
    const int b = r / NOC;
    const float* in = ks ? inB : inA;
    const int cN = ks ? cB : cA;
    const int bstr = ks ? bstrB : bstrA;
    float* P = ks ? P1 : P0;
    const float* wq0 = wsc + ((long)(ks * NOC + ocg) * cN) * 72;

    const int ox = threadIdx.x & 127;
    const int ry = (threadIdx.x >> 7) << 2;   // 0 or 4 (wave-uniform)
    const int oy0 = strip * 8 + ry;
    const int iyb = oy0 - 1;

    bool vy[6];
#pragma unroll
    for (int j = 0; j < 6; ++j) vy[j] = (unsigned)(iyb + j) < (unsigned)H;

    float acc[OCB][4];
#pragma unroll
    for (int o = 0; o < OCB; ++o)
#pragma unroll
        for (int j = 0; j < 4; ++j) acc[o][j] = 0.f;

    const float* pc = in + (long)b * bstr * H * W + (long)iyb * W;
    for (int c = 0; c < cN; ++c) {
        const float* wq = wq0 + c * 72;
#pragma unroll
        for (int kx = 0; kx < 3; ++kx) {
            const int ix = ox + kx - 1;
            const bool vx = (unsigned)ix < (unsigned)W;
            float rv[6];
#pragma unroll
            for (int j = 0; j < 6; ++j)
                rv[j] = (vx && vy[j]) ? pc[j * W + ix] : 0.f;
#pragma unroll
            for (int o = 0; o < OCB; ++o) {
#pragma unroll
                for (int ky = 0; ky < 3; ++ky) {
                    float wz = wq[kx * 24 + o * 3 + ky];   // uniform -> s_load
#pragma unroll
                    for (int j = 0; j < 4; ++j)
                        acc[o][j] = fmaf(rv[j + ky], wz, acc[o][j]);
                }
            }
        }
        pc += (long)H * W;
    }
#pragma unroll
    for (int o = 0; o < OCB; ++o) {
        long base = (((long)b * Cout + ocg * OCB + o) * H + oy0) * W + ox;
#pragma unroll
        for (int j = 0; j < 4; ++j) P[base + (long)j * W] = acc[o][j];
    }
}

// out = lrelu(bias + p0 + p1), vectorized x4 (same per-element math: bit-exact)
__global__ void fuse_add_k(const float* __restrict__ p0, const float* __restrict__ p1,
                           const float* __restrict__ bias, float* __restrict__ out) {
    long q = (long)blockIdx.x * 256 + threadIdx.x;
    if (q >= (long)(N_FEA / 4)) return;
    long idx = q * 4;
    int oc = (int)((idx >> 14) % 96);       // 16384 % 4 == 0 -> oc uniform over quad
    float bz = bias[oc];
    f4 a = *(const f4*)(p0 + idx);
    f4 b = *(const f4*)(p1 + idx);
    f4 r;
#pragma unroll
    for (int j = 0; j < 4; ++j) {
        float v = bz + a[j] + b[j];
        r[j] = v > 0.f ? v : 0.1f * v;
    }
    *(f4*)(out + idx) = r;
}

// ---- stride-2 direct conv, SGPR weights, no LDS, 1 output px/thread ----
template <int OCB>
__global__ __launch_bounds__(256) void conv_s2_px(
    const float* __restrict__ in, int Cin, int Hin, int Win,
    const float* __restrict__ wsc, const float* __restrict__ bias,
    float* __restrict__ out, int Cout, int relu,
    float* __restrict__ qq, float* __restrict__ qf2) {
    const int Hout = Hin >> 1, Wout = Win >> 1;
    const int rpb = 256 / Wout;              // rows per block (1 px/thread)
    const int strips = Hout / rpb;
    int bid = blockIdx.x;
    const int strip = bid % strips; bid /= strips;
    const int NOC = Cout / OCB;
    const int ocg = bid % NOC;
    const int b = bid / NOC;
    const int tid = threadIdx.x;
    const int ox = tid % Wout;
    const int oy = strip * rpb + tid / Wout;
    const int iy0 = oy * 2 - 1, ix0 = ox * 2 - 1;
    const float* wq0 = wsc + (long)(ocg * Cin) * (OCB * 9);

    float acc[OCB];
#pragma unroll
    for (int o = 0; o < OCB; ++o) acc[o] = bias[ocg * OCB + o];
    const bool vx0 = ix0 >= 0;               // only left col / top row can be OOB
    const bool vy0 = iy0 >= 0;

    const float* pc = in + (long)b * Cin * Hin * Win + (long)iy0 * Win + ix0;
    for (int c = 0; c < Cin; ++c) {
        float rv[3][3];
#pragma unroll
        for (int jr = 0; jr < 3; ++jr) {
            const float* row = pc + jr * Win;
            const bool vr = jr ? true : vy0;
            rv[jr][0] = (vr && vx0) ? row[0] : 0.f;
            rv[jr][1] = vr ? row[1] : 0.f;
            rv[jr][2] = vr ? row[2] : 0.f;
        }
        const float* wq = wq0 + c * (OCB * 9);
#pragma unroll
        for (int o = 0; o < OCB; ++o)
#pragma unroll
            for (int ky = 0; ky < 3; ++ky)
#pragma unroll
                for (int kx = 0; kx < 3; ++kx)
                    acc[o] = fmaf(rv[ky][kx], wq[o * 9 + ky * 3 + kx], acc[o]);
        pc += (long)Hin * Win;
    }
#pragma unroll
    for (int o = 0; o < OCB; ++o) {
        long idx = (((long)b * Cout + ocg * OCB + o) * Hout + oy) * Wout + ox;
        float a = acc[o];
        if (relu) a = a > 0.f ? a : 0.1f * a;
        out[idx] = a;
        if (qq) {
            float qv = rintf(a);
            qq[idx] = qv;
            qf2[idx] = qv;
        }
    }
}

// ---- ConvTranspose2d(96->96,k3,s2,p1,op1): 2x2 output quad per thread, ----
// SGPR weights [ocg][c][o][ky*3+kx], 4 coalesced loads/c serve all 9 taps.
template <int OCB, int HWC>
__global__ __launch_bounds__(256) void convt_quad(
    const float* __restrict__ in, const float* __restrict__ wsc,
    const float* __restrict__ bias, void* __restrict__ out,
    int Hin, int Win, int relu) {
    const int C = 96;
    const int Hout = 2 * Hin, Wout = 2 * Win;
    const int strips = (Hin * Win) / 256;
    int bid = blockIdx.x;
    const int strip = bid % strips; bid /= strips;
    const int NOC = C / OCB;
    const int ocg = bid % NOC;
    const int b = bid / NOC;
    const int idx = strip * 256 + threadIdx.x;
    const int iy = idx / Win, ix = idx % Win;
    const bool vr = (ix + 1) < Win, vd = (iy + 1) < Hin;
    const float* wq0 = wsc + (long)(ocg * C) * (OCB * 9);

    float acc[OCB][4];
#pragma unroll
    for (int o = 0; o < OCB; ++o) {
        float bz = bias[ocg * OCB + o];
#pragma unroll
        for (int j = 0; j < 4; ++j) acc[o][j] = bz;
    }
    const float* pc = in + (long)b * C * Hin * Win + (long)iy * Win + ix;
    for (int c = 0; c < C; ++c) {
        float i00 = pc[0];
        float i01 = vr ? pc[1] : 0.f;
        float i10 = vd ? pc[Win] : 0.f;
        float i11 = (vr && vd) ? pc[Win + 1] : 0.f;
        const float* wq = wq0 + c * (OCB * 9);
#pragma unroll
        for (int o = 0; o < OCB; ++o) {
            const float* w = wq + o * 9;
            acc[o][0] = fmaf(i00, w[4], acc[o][0]);
            acc[o][1] = fmaf(i01, w[3], fmaf(i00, w[5], acc[o][1]));
            acc[o][2] = fmaf(i10, w[1], fmaf(i00, w[7], acc[o][2]));
            acc[o][3] = fmaf(i11, w[0],
                        fmaf(i10, w[2],
                        fmaf(i01, w[6],
                        fmaf(i00, w[8], acc[o][3]))));
        }
        pc += (long)Hin * Win;
    }
#pragma unroll
    for (int o = 0; o < OCB; ++o) {
        int oc = ocg * OCB + o;
#pragma unroll
        for (int j = 0; j < 4; ++j) {
            float a = acc[o][j];
            if (relu) a = a > 0.f ? a : 0.1f * a;
            int oy = 2 * iy + (j >> 1), ox2 = 2 * ix + (j & 1);
            if (HWC)
                ((bf16*)out)[((long)b * Hout * Wout + (long)oy * Wout + ox2) * 96 + oc] =
                    __float2bfloat16(a);
            else
                ((float*)out)[(((long)b * C + oc) * Hout + oy) * Wout + ox2] = a;
        }
    }
}

// -------- combined weight transforms: 3x MFMA-B pack + dcn MFMA-B pack ------
__device__ __forceinline__ void packw(const float* __restrict__ w, bf16* __restrict__ wP,
                                      int Cin, int swap, long i) {
    const int cpt = Cin >> 5;
    int e = (int)(i & 7);
    int n16 = (int)((i >> 3) & 15);
    int q = (int)((i >> 7) & 3);
    long t = i >> 9;
    int ci = (int)(t % cpt); t /= cpt;
    int tap = (int)(t % 9);
    int g = (int)(t / 9);
    int oc = g * 16 + n16;
    int c = ci * 32 + q * 8 + e;
    int cs = swap ? (c + Cin / 2) % Cin : c;
    wP[i] = __float2bfloat16(w[((long)oc * Cin + cs) * 9 + tap]);
}
__global__ void wxform_all(const float* __restrict__ coffw, const float* __restrict__ ref1w,
                           const float* __restrict__ ref2w, const float* __restrict__ dcnw,
                           bf16* __restrict__ p_coff, bf16* __restrict__ p_ref1,
                           bf16* __restrict__ p_ref2, bf16* __restrict__ p_dcn) {
    const long n1 = 124416, n2 = 165888, n3 = 82944, n4 = 82944;
    long i = (long)blockIdx.x * 256 + threadIdx.x;
    if (i < n1) { packw(coffw, p_coff, 96, 0, i); return; }
    i -= n1;
    if (i < n2) { packw(ref1w, p_ref1, 192, 1, i); return; }
    i -= n2;
    if (i < n3) { packw(ref2w, p_ref2, 96, 0, i); return; }
    i -= n3;
    if (i < n4) {
        // dcn: K=864 GEMM-B pack [g][ci][lane][8]; k' = ci*32+q*8+e with
        // K-ordering k' = kk*96 + c  (matches deform's [px][kk][c] LDS layout)
        int e = (int)(i & 7);
        int n16 = (int)((i >> 3) & 15);
        int q = (int)((i >> 7) & 3);
        long t = i >> 9;
        int ci = (int)(t % 27);
        int g = (int)(t / 27);
        int kp = ci * 32 + q * 8 + e;     // k' in [0,864)
        int c = kp % 96, kk = kp / 96;
        p_dcn[i] = __float2bfloat16(dcnw[(long)(g * 16 + n16) * 864 + c * 9 + kk]);
    }
}

// -------- pack fp32 NCHW (96 ch) -> bf16 HWC via LDS transpose --------
// Tile = 64 px x 96 ch. Reads coalesced per-channel rows; writes contiguous
// 192B HWC runs. LDS row stride 102 shorts (51 dwords, odd) -> conflict-free.
__global__ __launch_bounds__(256) void pack_hwc(const float* __restrict__ src,
                                                bf16* __restrict__ dst,
                                                int HW, int Cs, int coff) {
    __shared__ short lt[64][102];
    int bid = blockIdx.x;
    const int tiles = HW >> 6;             // 256
    const int b = bid / tiles;
    const int px0 = (bid % tiles) << 6;
    const float* s = src + (long)b * 96 * HW + px0;
    for (int e = threadIdx.x; e < 96 * 64; e += 256) {
        int c = e >> 6, p = e & 63;
        bf16 h = __float2bfloat16(s[(long)c * HW + p]);
        lt[p][c] = *(short*)&h;
    }
    __syncthreads();
    short* d = (short*)(dst + ((long)b * HW + px0) * Cs + coff);
    for (int e = threadIdx.x; e < 96 * 64; e += 256) {
        int p = e / 96, c = e % 96;
        d[(long)p * Cs + c] = lt[p][c];
    }
}

// ----------------- MFMA implicit-GEMM 3x3 conv (stride 1, 128x128) -----------------
template <int EPI>
__global__ __launch_bounds__(256) void mconv(
    const bf16* __restrict__ X, const bf16* __restrict__ wP,
    const float* __restrict__ bias, void* __restrict__ out,
    const bf16* __restrict__ res,
    int Cin, int Cout, int H, int W, int relu) {
    const int HW = H * W;
    const int NG = Cout >> 4, split = (NG + 1) >> 1;
    int bid = blockIdx.x;
    const int nb = HW >> 6;
    const int pxb = (bid % nb) << 6;
    const int b = bid / nb;
    const int wave = threadIdx.x >> 6, lane = threadIdx.x & 63;
    const int mt = (wave >> 1) << 5;
    const int og0 = (wave & 1) ? split : 0;
    const int og1 = (wave & 1) ? NG : split;
    const int q = lane >> 4, n16 = lane & 15;
    const int pA0 = pxb + mt + n16, pA1 = pA0 + 16;
    const int oy0 = pA0 / W, ox0 = pA0 % W;
    const int oy1 = pA1 / W, ox1 = pA1 % W;
    const long ib = (long)b * HW * Cin;
    f4 acc0[5], acc1[5];
    const f4 z4 = {0.f, 0.f, 0.f, 0.f};
#pragma unroll
    for (int g = 0; g < 5; ++g) { acc0[g] = z4; acc1[g] = z4; }
    const s8 z8 = {0, 0, 0, 0, 0, 0, 0, 0};
    const int cpt = Cin >> 5;
    const int lofs = lane << 3;
    for (int tap = 0; tap < 9; ++tap) {
        const int ky = tap / 3 - 1, kx = tap % 3 - 1;
        const int iy0 = oy0 + ky, ix0 = ox0 + kx;
        const int iy1 = oy1 + ky, ix1 = ox1 + kx;
        const bool v0 = (unsigned)iy0 < (unsigned)H && (unsigned)ix0 < (unsigned)W;
        const bool v1 = (unsigned)iy1 < (unsigned)H && (unsigned)ix1 < (unsigned)W;
        const bf16* pa0 = X + ib + ((long)iy0 * W + ix0) * Cin + q * 8;
        const bf16* pa1 = X + ib + ((long)iy1 * W + ix1) * Cin + q * 8;
        for (int ci = 0; ci < cpt; ++ci) {
            const int c0 = ci << 5;
            s8 a0 = v0 ? *(const s8*)(pa0 + c0) : z8;
            s8 a1 = v1 ? *(const s8*)(pa1 + c0) : z8;
#pragma unroll
            for (int gi = 0; gi < 5; ++gi) {
                int g = og0 + gi;
                if (g >= og1) break;
                s8 bb = *(const s8*)(wP + ((long)(g * 9 + tap) * cpt + ci) * 512 + lofs);
                acc0[gi] = __builtin_amdgcn_mfma_f32_16x16x32_bf16(a0, bb, acc0[gi], 0, 0, 0);
                acc1[gi] = __builtin_amdgcn_mfma_f32_16x16x32_bf16(a1, bb, acc1[gi], 0, 0, 0);
            }
        }
    }
#pragma unroll
    for (int gi = 0; gi < 5; ++gi) {
        int g = og0 + gi;
        if (g >= og1) break;
        int oc = g * 16 + n16;
        float bz = bias[oc];
#pragma unroll
        for (int t = 0; t < 2; ++t) {
            f4 a = t ? acc1[gi] : acc0[gi];
            int pxl = pxb + mt + t * 16 + q * 4;
#pragma unroll
            for (int r = 0; r < 4; ++r) {
                float v = a[r] + bz;
                if (relu) v = v > 0.f ? v : 0.1f * v;
                int px = pxl + r;
                if (EPI == 0)
                    ((bf16*)out)[((long)b * HW + px) * Cout + oc] = __float2bfloat16(v);
                else {
                    v += b2f(res[((long)b * HW + px) * 192 + 96 + oc]);
                    ((float*)out)[((long)b * Cout + oc) * HW + px] = v;
                }
            }
        }
    }
}

// -------- DCNv1: group-vector bilinear sample + MFMA contraction.
// Block = 16 px of one row. Items = (px, g8, kk); each loads 12 contiguous
// channels per corner from ref in HWC bf16 (X2 ch 0..95). LDS s layout
// [px][kk*96+c]; wD packed to match. --------
__global__ __launch_bounds__(256, 4) void deform_m_k(
    const bf16* __restrict__ Xref, const bf16* __restrict__ offs,
    const bf16* __restrict__ wD, const float* __restrict__ db,
    bf16* __restrict__ X2) {
    const int H = 128, W = 128;
    __shared__ bf16 offL[16 * 144];
    __shared__ bf16 s[16][872];          // 864 + 8 pad
    int bid = blockIdx.x;
    const int band = bid & 7;            // XCD residue -> 16-row band
    int r = bid >> 3;
    const int b = r >> 7; r &= 127;
    const int rowin = r >> 3, xb = r & 7;
    const int oy = band * 16 + rowin;
    const int ox0 = xb * 16;
    const int tid = threadIdx.x;
    const long pxbase = (long)b * (H * W) + oy * W + ox0;
    // stage offsets (coalesced: lanes -> consecutive cc)
    for (int e = tid; e < 16 * 144; e += 256)
        offL[e] = offs[(pxbase + (e / 144)) * 144 + (e % 144)];
    __syncthreads();
    // phase 2: items (p, g8, kk); 12-channel vector bilinear from HWC bf16 ref
    const long refb = (long)b * (H * W);
    for (int e = tid; e < 16 * 72; e += 256) {
        int p = e / 72, rem = e % 72;
        int g8 = rem / 9, kk = rem % 9;
        int ox = ox0 + p;
        float offy = b2f(offL[p * 144 + g8 * 18 + kk * 2]);
        float offx = b2f(offL[p * 144 + g8 * 18 + kk * 2 + 1]);
        float py = (float)(oy + kk / 3 - 1) + offy;
        float px = (float)(ox + kk % 3 - 1) + offx;
        float y0f = floorf(py), x0f = floorf(px);
        float ly = py - y0f, lx = px - x0f;
        int y0 = (int)y0f, x0 = (int)x0f;
        float w00 = (1.f - ly) * (1.f - lx), w01 = (1.f - ly) * lx;
        float w10 = ly * (1.f - lx), w11 = ly * lx;
        float v[12];
#pragma unroll
        for (int j = 0; j < 12; ++j) v[j] = 0.f;
        auto corner = [&](int yy, int xx, float wgt) {
            if ((unsigned)yy < (unsigned)H && (unsigned)xx < (unsigned)W) {
                const s4* cp = (const s4*)(Xref + (refb + yy * W + xx) * 192 + g8 * 12);
                s4 c0 = cp[0], c1 = cp[1], c2 = cp[2];
#pragma unroll
                for (int j = 0; j < 4; ++j) {
                    v[j]     = fmaf(bs2f(c0[j]), wgt, v[j]);
                    v[4 + j] = fmaf(bs2f(c1[j]), wgt, v[4 + j]);
                    v[8 + j] = fmaf(bs2f(c2[j]), wgt, v[8 + j]);
                }
            }
        };
        corner(y0, x0, w00);
        corner(y0, x0 + 1, w01);
        corner(y0 + 1, x0, w10);
        corner(y0 + 1, x0 + 1, w11);
        short rr[12];
#pragma unroll
        for (int j = 0; j < 12; ++j) {
            bf16 h = __float2bfloat16(v[j]);
            rr[j] = *(short*)&h;
        }
        s4* dst = (s4*)&s[p][kk * 96 + g8 * 12];
        dst[0] = ((s4*)rr)[0];
        dst[1] = ((s4*)rr)[1];
        dst[2] = ((s4*)rr)[2];
    }
    __syncthreads();
    // phase 3: MFMA [16px x 864] x [864 x 96oc]; 6 tasks over 4 waves
    const int wave = tid >> 6, lane = tid & 63;
    const int q = lane >> 4, n16 = lane & 15;
    const f4 z4 = {0.f, 0.f, 0.f, 0.f};
    for (int g = wave; g < 6; g += 4) {
        f4 acc = z4;
        const bf16* wg = wD + (long)g * 27 * 512 + (lane << 3);
#pragma unroll 3
        for (int ci = 0; ci < 27; ++ci) {
            s8 a = *(const s8*)&s[n16][ci * 32 + q * 8];
            s8 bb = *(const s8*)(wg + ci * 512);
            acc = __builtin_amdgcn_mfma_f32_16x16x32_bf16(a, bb, acc, 0, 0, 0);
        }
        int oc = g * 16 + n16;
        float bz = db[oc];
#pragma unroll
        for (int rr2 = 0; rr2 < 4; ++rr2) {
            int p = q * 4 + rr2;           // D row = q*4 + reg
            X2[(pxbase + p) * 192 + 96 + oc] = __float2bfloat16(acc[rr2] + bz);
        }
    }
}

extern "C" void kernel_launch(void* const* d_in, const int* in_sizes, int n_in,
                              void* d_out, int out_size, void* d_ws, size_t ws_size,
                              hipStream_t stream) {
    const float* ref_fea = (const float*)d_in[0];
    const float* inp_fea = (const float*)d_in[1];
    const float* oc1_w = (const float*)d_in[2];  const float* oc1_b = (const float*)d_in[3];
    const float* oc3_w = (const float*)d_in[4];  const float* oc3_b = (const float*)d_in[5];
    const float* enc1_w = (const float*)d_in[6]; const float* enc1_b = (const float*)d_in[7];
    const float* enc2_w = (const float*)d_in[8]; const float* enc2_b = (const float*)d_in[9];
    const float* dec1_w = (const float*)d_in[10]; const float* dec1_b = (const float*)d_in[11];
    const float* dec2_w = (const float*)d_in[12]; const float* dec2_b = (const float*)d_in[13];
    const float* coff_w = (const float*)d_in[14]; const float* coff_b = (const float*)d_in[15];
    const float* dcn_w = (const float*)d_in[16];  const float* dcn_b = (const float*)d_in[17];
    const float* ref1_w = (const float*)d_in[18]; const float* ref1_b = (const float*)d_in[19];
    const float* ref2_w = (const float*)d_in[20]; const float* ref2_b = (const float*)d_in[21];

    float* out = (float*)d_out;
    float* OUTS = out;                    // out0 region as fp32 scratch (t1/t2)
    float* S1 = (float*)d_ws;             // 12.58 MB slot
    float* S2 = S1 + N_FEA;               // 12.58 MB slot
    float* F = S1 + N_E1;                 // q fp32 (after e1 region)
    bf16* de_hwc = (bf16*)S1;
    bf16* offs = (bf16*)S2;               // HWC [b][HW][144] (9.44 MB)
    bf16* X2 = (bf16*)S1;                 // [ref | aligned] HWC 192c
    bf16* r1 = (bf16*)S2;
    bf16* wtb = (bf16*)S2 + 4800000;      // tail at S2+9.6 MB
    bf16* wt_coff = wtb;                  // 124416
    bf16* wt_ref1 = wt_coff + 124416;     // 165888
    bf16* wt_ref2 = wt_ref1 + 165888;     // 82944
    bf16* wt_dcn = wt_ref2 + 82944;       // 82944 (MFMA-B pack)
    float* wdec1 = (float*)(wt_dcn + 82944);  // 82944 fp32 (dec1 quad pack)
    float* wdec2 = wdec1 + 82944;             // 82944 fp32 (dec2 quad pack)
    // scalar-weight packs for oc1/oc3 in the en/q output region (consumed
    // before enc2 overwrites it)
    float* wsc1 = out + OUT_EN;           // 165888 fp32
    float* wsc3 = wsc1 + 165888;          // 82944 fp32
    // enc weight packs in S1 tail (free after oc3 fuse; overwritten by X2
    // only after enc2 completes)
    float* wenc1 = S1 + 1048576;          // 82944 fp32
    float* wenc2 = wenc1 + 82944;         // 82944 fp32

    dim3 blk(256);
    auto nb = [](long n) { return dim3((unsigned)((n + 255) / 256)); };

    // ---- encoder (fp32-exact; split-K for occupancy) ----
    wpack_sw<<<nb(165888L + 82944), blk, 0, stream>>>(oc1_w, oc3_w, wsc1, wsc3);
    conv3x3_sw<8><<<dim3(768), blk, 0, stream>>>(ref_fea, 96, 96,
                                                 inp_fea, 96, 96,
                                                 wsc1, S1, S2, 96);
    fuse_add_k<<<dim3(3072), blk, 0, stream>>>(S1, S2, oc1_b, OUTS);
    conv3x3_sw<8><<<dim3(768), blk, 0, stream>>>(OUTS, 48, 96,
                                                 OUTS + 48 * 16384, 48, 96,
                                                 wsc3, S1, S2, 96);
    fuse_add_k<<<dim3(3072), blk, 0, stream>>>(S1, S2, oc3_b, OUTS);
    wpack_enc<<<nb(82944L + 82944), blk, 0, stream>>>(enc1_w, enc2_w, wenc1, wenc2);
    // enc1: 1 px/thread, OCB=4 -> 2*24*16 = 768 blocks (3/CU)
    conv_s2_px<4><<<dim3(768), blk, 0, stream>>>(OUTS, 96, 128, 128,
                                                 wenc1, enc1_b, S1, 96, 1,
                                                 nullptr, nullptr);
    wxform_all<<<nb(124416L + 165888 + 82944 + 82944), blk, 0, stream>>>(
        coff_w, ref1_w, ref2_w, dcn_w, wt_coff, wt_ref1, wt_ref2, wt_dcn);
    wpack_dec<<<nb(82944L + 82944), blk, 0, stream>>>(dec1_w, dec2_w, wdec1, wdec2);
    // enc2: 1 px/thread, OCB=2 -> 2*48*4 = 384 blocks
    conv_s2_px<2><<<dim3(384), blk, 0, stream>>>(S1, 96, 64, 64,
                                                 wenc2, enc2_b, out + OUT_EN, 96, 0,
                                                 out + OUT_Q, F);
    // ---- decoder: quad ConvT, SGPR weights ----
    // dec1: 32x32 input, OCB=2 -> 2*48*4 = 384 blocks, fp32 NCHW out
    convt_quad<2, 0><<<dim3(384), blk, 0, stream>>>(F, wdec1, dec1_b, S2, 32, 32, 1);
    // dec2: 64x64 input, OCB=4 -> 2*24*16 = 768 blocks, bf16 HWC out
    convt_quad<4, 1><<<dim3(768), blk, 0, stream>>>(S2, wdec2, dec2_b, de_hwc, 64, 64, 0);
    // ---- MFMA: offsets = conv(de) -> HWC bf16 ----
    mconv<0><<<dim3(512), blk, 0, stream>>>(de_hwc, wt_coff, coff_b, offs, nullptr,
                                            96, 144, 128, 128, 0);
    // ---- X2 = [ref | aligned] HWC (LDS-transpose pack) ----
    pack_hwc<<<dim3(512), blk, 0, stream>>>(ref_fea, X2, 16384, 192, 0);
    deform_m_k<<<dim3(2048), blk, 0, stream>>>(X2, offs, wt_dcn, dcn_b, X2);
    // ---- MFMA: r1 = lrelu(conv(X2, ref1)); out0 = aligned + lrelu(conv(r1, ref2)) ----
    mconv<0><<<dim3(512), blk, 0, stream>>>(X2, wt_ref1, ref1_b, r1, nullptr,
                                            192, 96, 128, 128, 1);
    mconv<3><<<dim3(512), blk, 0, stream>>>(r1, wt_ref2, ref2_b, out, X2,
                                            96, 96, 128, 128, 1);
}